// Round 10
// baseline (3006.520 us; speedup 1.0000x reference)
//
#include <hip/hip_runtime.h>

#define DIM 2048
#define LEAK 0.2f

typedef __bf16 bf16x8 __attribute__((ext_vector_type(8)));
typedef float  f32x4  __attribute__((ext_vector_type(4)));
typedef unsigned int u32x4 __attribute__((ext_vector_type(4)));
typedef int    i32x4  __attribute__((ext_vector_type(4)));

static __device__ __forceinline__ unsigned short f2bf(float f) {
    unsigned int x = __float_as_uint(f);
    return (unsigned short)((x + 0x7fffu + ((x >> 16) & 1u)) >> 16);  // RNE
}
static __device__ __forceinline__ float bf2f(unsigned short h) {
    return __uint_as_float(((unsigned int)h) << 16);
}

static __device__ __forceinline__ void async16(const void* g, void* s) {
    __builtin_amdgcn_global_load_lds(
        (const __attribute__((address_space(1))) void*)g,
        (__attribute__((address_space(3))) void*)s, 16, 0, 0);
}

static __device__ __forceinline__ bf16x8 ld_bf16_frag(const char* p) {
    union { u32x4 u; bf16x8 v; } cv;
    cv.u = *(const u32x4*)p;   // ds_read_b128
    return cv.v;
}

// ---------------- prep kernels ----------------

__global__ __launch_bounds__(256) void split_kernel(
    const float* __restrict__ in,
    unsigned short* __restrict__ hi, unsigned short* __restrict__ lo) {
    int idx = blockIdx.x * 256 + threadIdx.x;
    float4 v = ((const float4*)in)[idx];
    ushort4 h, l;
    h.x = f2bf(v.x); l.x = f2bf(v.x - bf2f(h.x));
    h.y = f2bf(v.y); l.y = f2bf(v.y - bf2f(h.y));
    h.z = f2bf(v.z); l.z = f2bf(v.z - bf2f(h.z));
    h.w = f2bf(v.w); l.w = f2bf(v.w - bf2f(h.w));
    ((ushort4*)hi)[idx] = h;
    ((ushort4*)lo)[idx] = l;
}

__global__ __launch_bounds__(256) void transpose_split(
    const float* __restrict__ in,
    unsigned short* __restrict__ hiT, unsigned short* __restrict__ loT) {
    __shared__ float t[32][33];
    int bx = blockIdx.x, by = blockIdx.y;
    int tx = threadIdx.x & 31, ty4 = (threadIdx.x >> 5) << 2;
#pragma unroll
    for (int i = 0; i < 4; i++)
        t[ty4 + i][tx] = in[(size_t)(by * 32 + ty4 + i) * DIM + bx * 32 + tx];
    __syncthreads();
#pragma unroll
    for (int i = 0; i < 4; i++) {
        float v = t[tx][ty4 + i];
        size_t o = (size_t)(bx * 32 + ty4 + i) * DIM + by * 32 + tx;
        unsigned short h = f2bf(v);
        hiT[o] = h;
        loT[o] = f2bf(v - bf2f(h));
    }
}

__global__ __launch_bounds__(256) void transpose_i8(
    const float* __restrict__ in, signed char* __restrict__ outT) {
    __shared__ float t[32][33];
    int bx = blockIdx.x, by = blockIdx.y;
    int tx = threadIdx.x & 31, ty4 = (threadIdx.x >> 5) << 2;
#pragma unroll
    for (int i = 0; i < 4; i++)
        t[ty4 + i][tx] = in[(size_t)(by * 32 + ty4 + i) * DIM + bx * 32 + tx];
    __syncthreads();
#pragma unroll
    for (int i = 0; i < 4; i++)
        outT[(size_t)(bx * 32 + ty4 + i) * DIM + by * 32 + tx] =
            (signed char)t[tx][ty4 + i];
}

__global__ __launch_bounds__(256) void quant_split(
    const float* __restrict__ in,
    signed char* __restrict__ hi, signed char* __restrict__ lo) {
    int idx = blockIdx.x * 256 + threadIdx.x;
    float4 v = ((const float4*)in)[idx];
    char4 h, l;
    {
        int q = (int)rintf(v.x * 16384.f); q = q > 16383 ? 16383 : (q < -16383 ? -16383 : q);
        h.x = (signed char)(q >> 7); l.x = (signed char)(q & 127);
    }
    {
        int q = (int)rintf(v.y * 16384.f); q = q > 16383 ? 16383 : (q < -16383 ? -16383 : q);
        h.y = (signed char)(q >> 7); l.y = (signed char)(q & 127);
    }
    {
        int q = (int)rintf(v.z * 16384.f); q = q > 16383 ? 16383 : (q < -16383 ? -16383 : q);
        h.z = (signed char)(q >> 7); l.z = (signed char)(q & 127);
    }
    {
        int q = (int)rintf(v.w * 16384.f); q = q > 16383 ? 16383 : (q < -16383 ? -16383 : q);
        h.w = (signed char)(q >> 7); l.w = (signed char)(q & 127);
    }
    ((char4*)hi)[idx] = h;
    ((char4*)lo)[idx] = l;
}

// ---------------- bf16 dual-A GEMM (drive) v9 (r9-proven, unchanged) ---------
// MODE 0: Cout = (Ahi+Alo) @ B^T        MODE 1: Cout = Cin + P + bias[n]
template <int MODE>
__global__ __launch_bounds__(512, 2) void gemm128(
    const unsigned short* __restrict__ Ahi,
    const unsigned short* __restrict__ Alo,
    const unsigned short* __restrict__ BT,
    const float* __restrict__ Cin,
    const float* __restrict__ bias,
    float* __restrict__ Cout) {
    __shared__ alignas(16) char lds[3][49152];   // per buf: A 32KB | B 16KB

    const int bid = blockIdx.x;                  // 256 blocks = 16x16 tiles
    const int xcd = bid & 7, slot = bid >> 3;
    const int tm = ((xcd >> 1) << 2) + (slot >> 3);   // 0..15
    const int tn = ((xcd & 1) << 3) + (slot & 7);     // 0..15
    const int row0 = tm << 7, col0 = tn << 7;

    const int tid = threadIdx.x;
    const int lane = tid & 63;
    const int quad = lane >> 4, l16 = lane & 15;
    const int wave = tid >> 6;
    const int wm = wave >> 1, wn = wave & 1;

    const unsigned short* a_src[4]; int a_dst[4];
    const unsigned short* b_src[2]; int b_dst[2];
#pragma unroll
    for (int i = 0; i < 4; i++) {
        int s = tid + 512 * i;                  // 0..2047: 128 rows x 2 pl x 8 ch
        int r = s >> 4, g = (s >> 3) & 1, c = (s & 7) ^ (r & 7);
        a_src[i] = (g ? Alo : Ahi) + (size_t)(row0 + r) * DIM + c * 8;
        a_dst[i] = s * 16;
    }
#pragma unroll
    for (int i = 0; i < 2; i++) {
        int s = tid + 512 * i;                  // 0..1023: 128 rows x 8 ch
        int r = s >> 3, c = (s & 7) ^ (r & 7);
        b_src[i] = BT + (size_t)(col0 + r) * DIM + c * 8;
        b_dst[i] = s * 16;
    }

    int aoff[2][2], boff[4][2];
#pragma unroll
    for (int i = 0; i < 2; i++)
#pragma unroll
        for (int kk = 0; kk < 2; kk++) {
            const int r = (wm << 5) + (i << 4) + l16;
            const int cs = ((kk << 2) + quad) ^ (r & 7);
            aoff[i][kk] = ((r << 4) + cs) * 16;           // hi; lo = +128
        }
#pragma unroll
    for (int j = 0; j < 4; j++)
#pragma unroll
        for (int kk = 0; kk < 2; kk++) {
            const int r = (wn << 6) + (j << 4) + l16;
            const int cs = ((kk << 2) + quad) ^ (r & 7);
            boff[j][kk] = ((r << 3) + cs) * 16;
        }

    f32x4 acc[2][4] = {};

    auto stage6 = [&](char* base, int k0) {      // k0 in bf16 elements
#pragma unroll
        for (int i = 0; i < 4; i++) async16(a_src[i] + k0, base + a_dst[i]);
#pragma unroll
        for (int i = 0; i < 2; i++) async16(b_src[i] + k0, base + 32768 + b_dst[i]);
    };

    stage6(lds[0], 0);
    stage6(lds[1], 64);
    asm volatile("s_waitcnt vmcnt(6)" ::: "memory");

    for (int t = 0; t < 32; ++t) {               // 32 K-tiles of 64 elems
        const char* A = lds[t % 3];
        const char* B = A + 32768;

        __builtin_amdgcn_s_barrier();            // publish buffer t
        __builtin_amdgcn_sched_barrier(0);
        if (t + 2 < 32) stage6(lds[(t + 2) % 3], (t + 2) << 6);

        bf16x8 ah[2][2], al[2][2], bv[4][2];
#pragma unroll
        for (int i = 0; i < 2; i++)
#pragma unroll
            for (int kk = 0; kk < 2; kk++) {
                ah[i][kk] = ld_bf16_frag(A + aoff[i][kk]);
                al[i][kk] = ld_bf16_frag(A + aoff[i][kk] + 128);
            }
#pragma unroll
        for (int j = 0; j < 4; j++)
#pragma unroll
            for (int kk = 0; kk < 2; kk++)
                bv[j][kk] = ld_bf16_frag(B + boff[j][kk]);

        __builtin_amdgcn_s_setprio(1);
#pragma unroll
        for (int i = 0; i < 2; i++)
#pragma unroll
            for (int j = 0; j < 4; j++)
#pragma unroll
                for (int kk = 0; kk < 2; kk++) {
                    acc[i][j] = __builtin_amdgcn_mfma_f32_16x16x32_bf16(ah[i][kk], bv[j][kk], acc[i][j], 0, 0, 0);
                    acc[i][j] = __builtin_amdgcn_mfma_f32_16x16x32_bf16(al[i][kk], bv[j][kk], acc[i][j], 0, 0, 0);
                }
        __builtin_amdgcn_s_setprio(0);

        __builtin_amdgcn_sched_barrier(0);
        if (t < 30)       asm volatile("s_waitcnt vmcnt(6)" ::: "memory");
        else if (t == 30) asm volatile("s_waitcnt vmcnt(0)" ::: "memory");
    }

#pragma unroll
    for (int i = 0; i < 2; i++) {
        const int rb = row0 + (wm << 5) + (i << 4) + (quad << 2);
#pragma unroll
        for (int j = 0; j < 4; j++) {
            const int c = col0 + (wn << 6) + (j << 4) + l16;
#pragma unroll
            for (int g = 0; g < 4; g++) {
                const size_t idx = (size_t)(rb + g) * DIM + c;
                if (MODE == 0) Cout[idx] = acc[i][j][g];
                else           Cout[idx] = Cin[idx] + acc[i][j][g] + bias[c];
            }
        }
    }
}

// ---------------- i8 recurrence step v10: A global->VGPR, B in LDS ----------
// r9's proven spine (128x128 block, 8 waves, tri-buffer, counted vmcnt
// certify-then-publish, setprio, compiler-counted lgkm) with A taken out of
// LDS: each lane loads its 8 A fragments (i x kk x plane, 16B each) straight
// from global ONE TILE AHEAD into a parity-indexed register set.  The t-loop
// is FULLY UNROLLED so all areg indices are compile-time (rule #20: no
// scratch -- r4's failure mode).  One wave A-load = 16 rows x 64B contiguous
// = full cache lines; the wn-pair's duplicate read hits L1.
// Removes per tile per CU: A LDS write 32KB + A LDS read 64KB (2/3 of all
// LDS traffic).  LDS now holds only B: tri-buffer 3 x 16KB.
// vmcnt bookkeeping: per tile issue {A(t+1):8, B(t+2):2}; end-of-tile
// vmcnt(10) waits exactly the 2 oldest = B(t+1) (certify) while leaving
// A(t+1)+B(t+2) in flight; A-register readiness is enforced by the
// compiler's own precise dep-waits (m97 behavior).  Never 0 in-loop.
__global__ __launch_bounds__(512, 2) void step_i8(
    const signed char* __restrict__ Ah,
    const signed char* __restrict__ Al,
    const signed char* __restrict__ BT,
    const float* __restrict__ drive,
    float* __restrict__ out,
    signed char* __restrict__ Oh,
    signed char* __restrict__ Ol,
    int write_f32) {
    __shared__ alignas(16) char lds[3][16384];   // B tri-buffer only

    const int bid = blockIdx.x;                  // 256 blocks = 16x16 tiles
    const int xcd = bid & 7, slot = bid >> 3;
    const int tm = ((xcd >> 1) << 2) + (slot >> 3);   // 0..15
    const int tn = ((xcd & 1) << 3) + (slot & 7);     // 0..15
    const int row0 = tm << 7, col0 = tn << 7;

    const int tid = threadIdx.x;
    const int lane = tid & 63;
    const int quad = lane >> 4, l16 = lane & 15;
    const int wave = tid >> 6;
    const int wm = wave >> 1;         // 0..3
    const int wn = wave & 1;          // 0..1

    // B staging (r9-identical): 2 x 16B async16 per thread per K-tile
    const signed char* b_src[2]; int b_dst[2];
#pragma unroll
    for (int i = 0; i < 2; i++) {
        int s = tid + 512 * i;                  // 0..1023: 128 rows x 8 ch
        int r = s >> 3, c = (s & 7) ^ (r & 7);
        b_src[i] = BT + (size_t)(col0 + r) * DIM + c * 16;
        b_dst[i] = s * 16;
    }

    // B fragment offsets (r9-identical swizzle)
    int boff[4][2];
#pragma unroll
    for (int j = 0; j < 4; j++)
#pragma unroll
        for (int kk = 0; kk < 2; kk++) {
            const int r = (wn << 6) + (j << 4) + l16;
            const int cs = ((kk << 2) + quad) ^ (r & 7);
            boff[j][kk] = ((r << 3) + cs) * 16;
        }

    // A per-lane global bases: row = row0 + wm*32 + i*16 + l16, K ofs quad*16.
    // One wave instr covers 16 rows x 64B contiguous (4 quads) = full lines.
    const signed char* aHp[2]; const signed char* aLp[2];
    {
        const size_t base = (size_t)(row0 + (wm << 5) + l16) * DIM + (quad << 4);
        aHp[0] = Ah + base;                    aLp[0] = Al + base;
        aHp[1] = Ah + base + (size_t)16 * DIM; aLp[1] = Al + base + (size_t)16 * DIM;
    }

    i32x4 areg[2][2][2][2];   // [t&1][i][kk][plane] -- all indices const (full unroll)
    i32x4 acch[2][4] = {};
    i32x4 accl[2][4] = {};
    float dreg[2][4][4];

    // prologue: issue order B(0):2 (oldest), A(0):8, B(1):2 (newest)
#pragma unroll
    for (int i = 0; i < 2; i++) async16(b_src[i], lds[0] + b_dst[i]);
#pragma unroll
    for (int i = 0; i < 2; i++)
#pragma unroll
        for (int kk = 0; kk < 2; kk++) {
            areg[0][i][kk][0] = *(const i32x4*)(aHp[i] + (kk << 6));
            areg[0][i][kk][1] = *(const i32x4*)(aLp[i] + (kk << 6));
        }
#pragma unroll
    for (int i = 0; i < 2; i++) async16(b_src[i] + 128, lds[1] + b_dst[i]);
    asm volatile("s_waitcnt vmcnt(10)" ::: "memory");   // B(0) landed

#pragma unroll
    for (int t = 0; t < 16; ++t) {
        const char* B = lds[t % 3];

        __builtin_amdgcn_s_barrier();            // publish B(t)
        __builtin_amdgcn_sched_barrier(0);

        if (t + 1 < 16) {                        // A(t+1) -> other parity set
#pragma unroll
            for (int i = 0; i < 2; i++)
#pragma unroll
                for (int kk = 0; kk < 2; kk++) {
                    areg[(t + 1) & 1][i][kk][0] =
                        *(const i32x4*)(aHp[i] + ((t + 1) << 7) + (kk << 6));
                    areg[(t + 1) & 1][i][kk][1] =
                        *(const i32x4*)(aLp[i] + ((t + 1) << 7) + (kk << 6));
                }
        }
        if (t + 2 < 16) {                        // stage B(t+2)
#pragma unroll
            for (int i = 0; i < 2; i++)
                async16(b_src[i] + ((t + 2) << 7), lds[(t + 2) % 3] + b_dst[i]);
        }
        __builtin_amdgcn_sched_barrier(0);

        if (t == 15) {
            // epilogue drive prefetch under the last tile's MFMAs
#pragma unroll
            for (int i = 0; i < 2; i++) {
                const int rb = row0 + (wm << 5) + (i << 4) + (quad << 2);
#pragma unroll
                for (int j = 0; j < 4; j++) {
                    const int c = col0 + (wn << 6) + (j << 4) + l16;
#pragma unroll
                    for (int g = 0; g < 4; g++)
                        dreg[i][j][g] = drive[(size_t)(rb + g) * DIM + c];
                }
            }
        }

        i32x4 bv[4][2];
#pragma unroll
        for (int j = 0; j < 4; j++)
#pragma unroll
            for (int kk = 0; kk < 2; kk++)
                bv[j][kk] = *(const i32x4*)(B + boff[j][kk]);

        __builtin_amdgcn_s_setprio(1);
#pragma unroll
        for (int i = 0; i < 2; i++)
#pragma unroll
            for (int j = 0; j < 4; j++)
#pragma unroll
                for (int kk = 0; kk < 2; kk++) {
                    acch[i][j] = __builtin_amdgcn_mfma_i32_16x16x64_i8(
                        areg[t & 1][i][kk][0], bv[j][kk], acch[i][j], 0, 0, 0);
                    accl[i][j] = __builtin_amdgcn_mfma_i32_16x16x64_i8(
                        areg[t & 1][i][kk][1], bv[j][kk], accl[i][j], 0, 0, 0);
                }
        __builtin_amdgcn_s_setprio(0);
        __builtin_amdgcn_sched_barrier(0);

        // certify B(t+1) (the 2 oldest); leave A(t+1):8 + B(t+2):2 in flight
        if (t < 14)       asm volatile("s_waitcnt vmcnt(10)" ::: "memory");
        else if (t == 14) asm volatile("s_waitcnt vmcnt(8)" ::: "memory");
    }

    // epilogue: r0-identical math; drive from registers
#pragma unroll
    for (int i = 0; i < 2; i++) {
        const int rb = row0 + (wm << 5) + (i << 4) + (quad << 2);
#pragma unroll
        for (int j = 0; j < 4; j++) {
            const int c = col0 + (wn << 6) + (j << 4) + l16;
#pragma unroll
            for (int g = 0; g < 4; g++) {
                const size_t idx = (size_t)(rb + g) * DIM + c;
                int prod = acch[i][j][g] * 128 + accl[i][j][g];   // exact int
                float y = dreg[i][j][g] + (float)prod * (1.0f / 16384.0f);
                float sold = (float)((int)Ah[idx] * 128 + (int)Al[idx]) * (1.0f / 16384.0f);
                float e = __expf(2.0f * y);
                float th = 1.0f - 2.0f / (e + 1.0f);
                float s = (1.0f - LEAK) * sold + LEAK * th;
                if (write_f32) out[idx] = s;
                int q = (int)rintf(s * 16384.f);
                q = q > 16383 ? 16383 : (q < -16383 ? -16383 : q);
                Oh[idx] = (signed char)(q >> 7);
                Ol[idx] = (signed char)(q & 127);
            }
        }
    }
}

extern "C" void kernel_launch(void* const* d_in, const int* in_sizes, int n_in,
                              void* d_out, int out_size, void* d_ws, size_t ws_size,
                              hipStream_t stream) {
    const float* x    = (const float*)d_in[0];
    const float* wgt  = (const float*)d_in[1];
    const float* adj  = (const float*)d_in[2];
    const float* bias = (const float*)d_in[3];
    const float* st0  = (const float*)d_in[4];
    float* out = (float*)d_out;

    const size_t NE = (size_t)DIM * DIM;
    // ws (52 MB): adjT_i8(4) | drive(16) | bufA..bufD bf16(32);
    // i8 state ping-pong (4x4MB) aliases bufA/bufB after drive GEMMs retire.
    signed char* adjT = (signed char*)d_ws;
    float* drive = (float*)(adjT + NE);
    unsigned short* bufA = (unsigned short*)(drive + NE);
    unsigned short* bufB = bufA + NE;
    unsigned short* bufC = bufB + NE;
    unsigned short* bufD = bufC + NE;
    signed char* h1 = (signed char*)bufA;
    signed char* l1 = h1 + NE;
    signed char* h2 = l1 + NE;
    signed char* l2 = h2 + NE;

    dim3 blk(256);
    transpose_split<<<dim3(64, 64), blk, 0, stream>>>(wgt, bufC, bufD);
    split_kernel<<<dim3(4096), blk, 0, stream>>>(x, bufA, bufB);
    transpose_i8<<<dim3(64, 64), blk, 0, stream>>>(adj, adjT);

    gemm128<0><<<dim3(256), dim3(512), 0, stream>>>(bufA, bufB, bufC, (const float*)0,
                                                    (const float*)0, drive);
    gemm128<1><<<dim3(256), dim3(512), 0, stream>>>(bufA, bufB, bufD, drive, bias, drive);

    quant_split<<<dim3(4096), blk, 0, stream>>>(st0, h1, l1);

    signed char* hi = h1; signed char* li = l1;
    signed char* ho = h2; signed char* lo = l2;
    for (int t = 0; t < 64; t++) {
        step_i8<<<dim3(256), dim3(512), 0, stream>>>(hi, li, adjT, drive, out,
                                                     ho, lo, (t == 63) ? 1 : 0);
        signed char* th = hi; hi = ho; ho = th;
        signed char* tl = li; li = lo; lo = tl;
    }
}

// Round 11
// 1549.545 us; speedup vs baseline: 1.9403x; 1.9403x over previous
//
#include <hip/hip_runtime.h>

#define DIM 2048
#define LEAK 0.2f

typedef __bf16 bf16x8 __attribute__((ext_vector_type(8)));
typedef float  f32x4  __attribute__((ext_vector_type(4)));
typedef unsigned int u32x4 __attribute__((ext_vector_type(4)));
typedef int    i32x4  __attribute__((ext_vector_type(4)));

static __device__ __forceinline__ unsigned short f2bf(float f) {
    unsigned int x = __float_as_uint(f);
    return (unsigned short)((x + 0x7fffu + ((x >> 16) & 1u)) >> 16);  // RNE
}
static __device__ __forceinline__ float bf2f(unsigned short h) {
    return __uint_as_float(((unsigned int)h) << 16);
}

static __device__ __forceinline__ void async16(const void* g, void* s) {
    __builtin_amdgcn_global_load_lds(
        (const __attribute__((address_space(1))) void*)g,
        (__attribute__((address_space(3))) void*)s, 16, 0, 0);
}

static __device__ __forceinline__ bf16x8 ld_bf16_frag(const char* p) {
    union { u32x4 u; bf16x8 v; } cv;
    cv.u = *(const u32x4*)p;   // ds_read_b128
    return cv.v;
}

// ---------------- prep kernels ----------------

__global__ __launch_bounds__(256) void split_kernel(
    const float* __restrict__ in,
    unsigned short* __restrict__ hi, unsigned short* __restrict__ lo) {
    int idx = blockIdx.x * 256 + threadIdx.x;
    float4 v = ((const float4*)in)[idx];
    ushort4 h, l;
    h.x = f2bf(v.x); l.x = f2bf(v.x - bf2f(h.x));
    h.y = f2bf(v.y); l.y = f2bf(v.y - bf2f(h.y));
    h.z = f2bf(v.z); l.z = f2bf(v.z - bf2f(h.z));
    h.w = f2bf(v.w); l.w = f2bf(v.w - bf2f(h.w));
    ((ushort4*)hi)[idx] = h;
    ((ushort4*)lo)[idx] = l;
}

__global__ __launch_bounds__(256) void transpose_split(
    const float* __restrict__ in,
    unsigned short* __restrict__ hiT, unsigned short* __restrict__ loT) {
    __shared__ float t[32][33];
    int bx = blockIdx.x, by = blockIdx.y;
    int tx = threadIdx.x & 31, ty4 = (threadIdx.x >> 5) << 2;
#pragma unroll
    for (int i = 0; i < 4; i++)
        t[ty4 + i][tx] = in[(size_t)(by * 32 + ty4 + i) * DIM + bx * 32 + tx];
    __syncthreads();
#pragma unroll
    for (int i = 0; i < 4; i++) {
        float v = t[tx][ty4 + i];
        size_t o = (size_t)(bx * 32 + ty4 + i) * DIM + by * 32 + tx;
        unsigned short h = f2bf(v);
        hiT[o] = h;
        loT[o] = f2bf(v - bf2f(h));
    }
}

__global__ __launch_bounds__(256) void transpose_i8(
    const float* __restrict__ in, signed char* __restrict__ outT) {
    __shared__ float t[32][33];
    int bx = blockIdx.x, by = blockIdx.y;
    int tx = threadIdx.x & 31, ty4 = (threadIdx.x >> 5) << 2;
#pragma unroll
    for (int i = 0; i < 4; i++)
        t[ty4 + i][tx] = in[(size_t)(by * 32 + ty4 + i) * DIM + bx * 32 + tx];
    __syncthreads();
#pragma unroll
    for (int i = 0; i < 4; i++)
        outT[(size_t)(bx * 32 + ty4 + i) * DIM + by * 32 + tx] =
            (signed char)t[tx][ty4 + i];
}

__global__ __launch_bounds__(256) void quant_split(
    const float* __restrict__ in,
    signed char* __restrict__ hi, signed char* __restrict__ lo) {
    int idx = blockIdx.x * 256 + threadIdx.x;
    float4 v = ((const float4*)in)[idx];
    char4 h, l;
    {
        int q = (int)rintf(v.x * 16384.f); q = q > 16383 ? 16383 : (q < -16383 ? -16383 : q);
        h.x = (signed char)(q >> 7); l.x = (signed char)(q & 127);
    }
    {
        int q = (int)rintf(v.y * 16384.f); q = q > 16383 ? 16383 : (q < -16383 ? -16383 : q);
        h.y = (signed char)(q >> 7); l.y = (signed char)(q & 127);
    }
    {
        int q = (int)rintf(v.z * 16384.f); q = q > 16383 ? 16383 : (q < -16383 ? -16383 : q);
        h.z = (signed char)(q >> 7); l.z = (signed char)(q & 127);
    }
    {
        int q = (int)rintf(v.w * 16384.f); q = q > 16383 ? 16383 : (q < -16383 ? -16383 : q);
        h.w = (signed char)(q >> 7); l.w = (signed char)(q & 127);
    }
    ((char4*)hi)[idx] = h;
    ((char4*)lo)[idx] = l;
}

// ---------------- bf16 dual-A GEMM (drive) v9 (r9-proven, unchanged) ---------
// MODE 0: Cout = (Ahi+Alo) @ B^T        MODE 1: Cout = Cin + P + bias[n]
template <int MODE>
__global__ __launch_bounds__(512, 2) void gemm128(
    const unsigned short* __restrict__ Ahi,
    const unsigned short* __restrict__ Alo,
    const unsigned short* __restrict__ BT,
    const float* __restrict__ Cin,
    const float* __restrict__ bias,
    float* __restrict__ Cout) {
    __shared__ alignas(16) char lds[3][49152];   // per buf: A 32KB | B 16KB

    const int bid = blockIdx.x;                  // 256 blocks = 16x16 tiles
    const int xcd = bid & 7, slot = bid >> 3;
    const int tm = ((xcd >> 1) << 2) + (slot >> 3);   // 0..15
    const int tn = ((xcd & 1) << 3) + (slot & 7);     // 0..15
    const int row0 = tm << 7, col0 = tn << 7;

    const int tid = threadIdx.x;
    const int lane = tid & 63;
    const int quad = lane >> 4, l16 = lane & 15;
    const int wave = tid >> 6;
    const int wm = wave >> 1, wn = wave & 1;

    const unsigned short* a_src[4]; int a_dst[4];
    const unsigned short* b_src[2]; int b_dst[2];
#pragma unroll
    for (int i = 0; i < 4; i++) {
        int s = tid + 512 * i;                  // 0..2047: 128 rows x 2 pl x 8 ch
        int r = s >> 4, g = (s >> 3) & 1, c = (s & 7) ^ (r & 7);
        a_src[i] = (g ? Alo : Ahi) + (size_t)(row0 + r) * DIM + c * 8;
        a_dst[i] = s * 16;
    }
#pragma unroll
    for (int i = 0; i < 2; i++) {
        int s = tid + 512 * i;                  // 0..1023: 128 rows x 8 ch
        int r = s >> 3, c = (s & 7) ^ (r & 7);
        b_src[i] = BT + (size_t)(col0 + r) * DIM + c * 8;
        b_dst[i] = s * 16;
    }

    int aoff[2][2], boff[4][2];
#pragma unroll
    for (int i = 0; i < 2; i++)
#pragma unroll
        for (int kk = 0; kk < 2; kk++) {
            const int r = (wm << 5) + (i << 4) + l16;
            const int cs = ((kk << 2) + quad) ^ (r & 7);
            aoff[i][kk] = ((r << 4) + cs) * 16;           // hi; lo = +128
        }
#pragma unroll
    for (int j = 0; j < 4; j++)
#pragma unroll
        for (int kk = 0; kk < 2; kk++) {
            const int r = (wn << 6) + (j << 4) + l16;
            const int cs = ((kk << 2) + quad) ^ (r & 7);
            boff[j][kk] = ((r << 3) + cs) * 16;
        }

    f32x4 acc[2][4] = {};

    auto stage6 = [&](char* base, int k0) {      // k0 in bf16 elements
#pragma unroll
        for (int i = 0; i < 4; i++) async16(a_src[i] + k0, base + a_dst[i]);
#pragma unroll
        for (int i = 0; i < 2; i++) async16(b_src[i] + k0, base + 32768 + b_dst[i]);
    };

    stage6(lds[0], 0);
    stage6(lds[1], 64);
    asm volatile("s_waitcnt vmcnt(6)" ::: "memory");

    for (int t = 0; t < 32; ++t) {               // 32 K-tiles of 64 elems
        const char* A = lds[t % 3];
        const char* B = A + 32768;

        __builtin_amdgcn_s_barrier();            // publish buffer t
        __builtin_amdgcn_sched_barrier(0);
        if (t + 2 < 32) stage6(lds[(t + 2) % 3], (t + 2) << 6);

        bf16x8 ah[2][2], al[2][2], bv[4][2];
#pragma unroll
        for (int i = 0; i < 2; i++)
#pragma unroll
            for (int kk = 0; kk < 2; kk++) {
                ah[i][kk] = ld_bf16_frag(A + aoff[i][kk]);
                al[i][kk] = ld_bf16_frag(A + aoff[i][kk] + 128);
            }
#pragma unroll
        for (int j = 0; j < 4; j++)
#pragma unroll
            for (int kk = 0; kk < 2; kk++)
                bv[j][kk] = ld_bf16_frag(B + boff[j][kk]);

        __builtin_amdgcn_s_setprio(1);
#pragma unroll
        for (int i = 0; i < 2; i++)
#pragma unroll
            for (int j = 0; j < 4; j++)
#pragma unroll
                for (int kk = 0; kk < 2; kk++) {
                    acc[i][j] = __builtin_amdgcn_mfma_f32_16x16x32_bf16(ah[i][kk], bv[j][kk], acc[i][j], 0, 0, 0);
                    acc[i][j] = __builtin_amdgcn_mfma_f32_16x16x32_bf16(al[i][kk], bv[j][kk], acc[i][j], 0, 0, 0);
                }
        __builtin_amdgcn_s_setprio(0);

        __builtin_amdgcn_sched_barrier(0);
        if (t < 30)       asm volatile("s_waitcnt vmcnt(6)" ::: "memory");
        else if (t == 30) asm volatile("s_waitcnt vmcnt(0)" ::: "memory");
    }

#pragma unroll
    for (int i = 0; i < 2; i++) {
        const int rb = row0 + (wm << 5) + (i << 4) + (quad << 2);
#pragma unroll
        for (int j = 0; j < 4; j++) {
            const int c = col0 + (wn << 6) + (j << 4) + l16;
#pragma unroll
            for (int g = 0; g < 4; g++) {
                const size_t idx = (size_t)(rb + g) * DIM + c;
                if (MODE == 0) Cout[idx] = acc[i][j][g];
                else           Cout[idx] = Cin[idx] + acc[i][j][g] + bias[c];
            }
        }
    }
}

// ---------------- i8 recurrence step v11: r9 spine + full epilogue prefetch --
// Exact revert to the r9 champion (A+B in tri-buffered LDS, one barrier per
// K-tile, counted vmcnt(6) certify-then-publish never 0 in-loop, setprio,
// compiler-counted lgkm).  Single addition: at t==15 (staging drained by the
// t==14 vmcnt(0)) prefetch BOTH epilogue input chains -- drive AND the sold
// bytes (combined immediately into 32 packed floats, +32 VGPR) -- so the
// epilogue is pure VALU+store.  r10's A-in-VGPR lane is closed (2x scratch
// spill: WRITE_SIZE 8.3 -> 26 MB sentinel).
__global__ __launch_bounds__(512, 2) void step_i8(
    const signed char* __restrict__ Ah,
    const signed char* __restrict__ Al,
    const signed char* __restrict__ BT,
    const float* __restrict__ drive,
    float* __restrict__ out,
    signed char* __restrict__ Oh,
    signed char* __restrict__ Ol,
    int write_f32) {
    __shared__ alignas(16) char lds[3][49152];   // per buf: A 32KB | B 16KB

    const int bid = blockIdx.x;                  // 256 blocks = 16x16 tiles
    const int xcd = bid & 7, slot = bid >> 3;
    const int tm = ((xcd >> 1) << 2) + (slot >> 3);   // 0..15
    const int tn = ((xcd & 1) << 3) + (slot & 7);     // 0..15
    const int row0 = tm << 7, col0 = tn << 7;

    const int tid = threadIdx.x;
    const int lane = tid & 63;
    const int quad = lane >> 4, l16 = lane & 15;
    const int wave = tid >> 6;
    const int wm = wave >> 1;         // 0..3
    const int wn = wave & 1;          // 0..1

    const signed char* a_src[4]; int a_dst[4];
    const signed char* b_src[2]; int b_dst[2];
#pragma unroll
    for (int i = 0; i < 4; i++) {
        int s = tid + 512 * i;                  // 0..2047
        int r = s >> 4, g = (s >> 3) & 1, c = (s & 7) ^ (r & 7);
        a_src[i] = (g ? Al : Ah) + (size_t)(row0 + r) * DIM + c * 16;
        a_dst[i] = s * 16;
    }
#pragma unroll
    for (int i = 0; i < 2; i++) {
        int s = tid + 512 * i;                  // 0..1023
        int r = s >> 3, c = (s & 7) ^ (r & 7);
        b_src[i] = BT + (size_t)(col0 + r) * DIM + c * 16;
        b_dst[i] = s * 16;
    }

    int aoff[2][2], boff[4][2];
#pragma unroll
    for (int i = 0; i < 2; i++)
#pragma unroll
        for (int kk = 0; kk < 2; kk++) {
            const int r = (wm << 5) + (i << 4) + l16;
            const int cs = ((kk << 2) + quad) ^ (r & 7);
            aoff[i][kk] = ((r << 4) + cs) * 16;           // hi; lo = +128
        }
#pragma unroll
    for (int j = 0; j < 4; j++)
#pragma unroll
        for (int kk = 0; kk < 2; kk++) {
            const int r = (wn << 6) + (j << 4) + l16;
            const int cs = ((kk << 2) + quad) ^ (r & 7);
            boff[j][kk] = ((r << 3) + cs) * 16;
        }

    i32x4 acch[2][4] = {};
    i32x4 accl[2][4] = {};
    float dreg[2][4][4];
    float soldreg[2][4][4];

    auto stage6 = [&](char* base, int k0) {
#pragma unroll
        for (int i = 0; i < 4; i++) async16(a_src[i] + k0, base + a_dst[i]);
#pragma unroll
        for (int i = 0; i < 2; i++) async16(b_src[i] + k0, base + 32768 + b_dst[i]);
    };

    stage6(lds[0], 0);
    stage6(lds[1], 128);
    asm volatile("s_waitcnt vmcnt(6)" ::: "memory");

    for (int t = 0; t < 16; ++t) {
        const char* A = lds[t % 3];
        const char* B = A + 32768;

        __builtin_amdgcn_s_barrier();            // publish buffer t
        __builtin_amdgcn_sched_barrier(0);
        if (t + 2 < 16) stage6(lds[(t + 2) % 3], (t + 2) << 7);

        if (t == 15) {
            // epilogue prefetch: staging drained (t=14 vmcnt(0)) => these are
            // the only outstanding VMEM ops; compiler inserts precise waits.
#pragma unroll
            for (int i = 0; i < 2; i++) {
                const int rb = row0 + (wm << 5) + (i << 4) + (quad << 2);
#pragma unroll
                for (int j = 0; j < 4; j++) {
                    const int c = col0 + (wn << 6) + (j << 4) + l16;
#pragma unroll
                    for (int g = 0; g < 4; g++) {
                        const size_t idx = (size_t)(rb + g) * DIM + c;
                        dreg[i][j][g] = drive[idx];
                        soldreg[i][j][g] =
                            (float)((int)Ah[idx] * 128 + (int)Al[idx]) *
                            (1.0f / 16384.0f);
                    }
                }
            }
        }

        i32x4 ah[2][2], al[2][2], bv[4][2];
#pragma unroll
        for (int i = 0; i < 2; i++)
#pragma unroll
            for (int kk = 0; kk < 2; kk++) {
                ah[i][kk] = *(const i32x4*)(A + aoff[i][kk]);
                al[i][kk] = *(const i32x4*)(A + aoff[i][kk] + 128);
            }
#pragma unroll
        for (int j = 0; j < 4; j++)
#pragma unroll
            for (int kk = 0; kk < 2; kk++)
                bv[j][kk] = *(const i32x4*)(B + boff[j][kk]);

        __builtin_amdgcn_s_setprio(1);
#pragma unroll
        for (int i = 0; i < 2; i++)
#pragma unroll
            for (int j = 0; j < 4; j++)
#pragma unroll
                for (int kk = 0; kk < 2; kk++) {
                    acch[i][j] = __builtin_amdgcn_mfma_i32_16x16x64_i8(ah[i][kk], bv[j][kk], acch[i][j], 0, 0, 0);
                    accl[i][j] = __builtin_amdgcn_mfma_i32_16x16x64_i8(al[i][kk], bv[j][kk], accl[i][j], 0, 0, 0);
                }
        __builtin_amdgcn_s_setprio(0);

        __builtin_amdgcn_sched_barrier(0);
        if (t < 14)       asm volatile("s_waitcnt vmcnt(6)" ::: "memory");
        else if (t == 14) asm volatile("s_waitcnt vmcnt(0)" ::: "memory");
    }

    // epilogue: pure VALU + stores (drive and sold already in registers)
#pragma unroll
    for (int i = 0; i < 2; i++) {
        const int rb = row0 + (wm << 5) + (i << 4) + (quad << 2);
#pragma unroll
        for (int j = 0; j < 4; j++) {
            const int c = col0 + (wn << 6) + (j << 4) + l16;
#pragma unroll
            for (int g = 0; g < 4; g++) {
                const size_t idx = (size_t)(rb + g) * DIM + c;
                int prod = acch[i][j][g] * 128 + accl[i][j][g];   // exact int
                float y = dreg[i][j][g] + (float)prod * (1.0f / 16384.0f);
                float e = __expf(2.0f * y);
                float th = 1.0f - 2.0f / (e + 1.0f);
                float s = (1.0f - LEAK) * soldreg[i][j][g] + LEAK * th;
                if (write_f32) out[idx] = s;
                int q = (int)rintf(s * 16384.f);
                q = q > 16383 ? 16383 : (q < -16383 ? -16383 : q);
                Oh[idx] = (signed char)(q >> 7);
                Ol[idx] = (signed char)(q & 127);
            }
        }
    }
}

extern "C" void kernel_launch(void* const* d_in, const int* in_sizes, int n_in,
                              void* d_out, int out_size, void* d_ws, size_t ws_size,
                              hipStream_t stream) {
    const float* x    = (const float*)d_in[0];
    const float* wgt  = (const float*)d_in[1];
    const float* adj  = (const float*)d_in[2];
    const float* bias = (const float*)d_in[3];
    const float* st0  = (const float*)d_in[4];
    float* out = (float*)d_out;

    const size_t NE = (size_t)DIM * DIM;
    // ws (52 MB): adjT_i8(4) | drive(16) | bufA..bufD bf16(32);
    // i8 state ping-pong (4x4MB) aliases bufA/bufB after drive GEMMs retire.
    signed char* adjT = (signed char*)d_ws;
    float* drive = (float*)(adjT + NE);
    unsigned short* bufA = (unsigned short*)(drive + NE);
    unsigned short* bufB = bufA + NE;
    unsigned short* bufC = bufB + NE;
    unsigned short* bufD = bufC + NE;
    signed char* h1 = (signed char*)bufA;
    signed char* l1 = h1 + NE;
    signed char* h2 = l1 + NE;
    signed char* l2 = h2 + NE;

    dim3 blk(256);
    transpose_split<<<dim3(64, 64), blk, 0, stream>>>(wgt, bufC, bufD);
    split_kernel<<<dim3(4096), blk, 0, stream>>>(x, bufA, bufB);
    transpose_i8<<<dim3(64, 64), blk, 0, stream>>>(adj, adjT);

    gemm128<0><<<dim3(256), dim3(512), 0, stream>>>(bufA, bufB, bufC, (const float*)0,
                                                    (const float*)0, drive);
    gemm128<1><<<dim3(256), dim3(512), 0, stream>>>(bufA, bufB, bufD, drive, bias, drive);

    quant_split<<<dim3(4096), blk, 0, stream>>>(st0, h1, l1);

    signed char* hi = h1; signed char* li = l1;
    signed char* ho = h2; signed char* lo = l2;
    for (int t = 0; t < 64; t++) {
        step_i8<<<dim3(256), dim3(512), 0, stream>>>(hi, li, adjT, drive, out,
                                                     ho, lo, (t == 63) ? 1 : 0);
        signed char* th = hi; hi = ho; ho = th;
        signed char* tl = li; li = lo; lo = tl;
    }
}